// Round 1
// baseline (218.763 us; speedup 1.0000x reference)
//
#include <hip/hip_runtime.h>

// ---------------- types ----------------
typedef __attribute__((ext_vector_type(8)))  __bf16 bf16x8;
typedef __attribute__((ext_vector_type(16))) float  f32x16;

struct U4 { unsigned int x, y, z, w; };

static __device__ __forceinline__ unsigned short f2bf(float f){
  unsigned int u = __builtin_bit_cast(unsigned int, f);
  u += 0x7fffu + ((u >> 16) & 1u);          // round-to-nearest-even
  return (unsigned short)(u >> 16);
}

static __device__ __forceinline__ bf16x8 ldfrag(const void* p){
  U4 v = *(const U4*)p;                      // ds_read_b128 / global_load_dwordx4
  return __builtin_bit_cast(bf16x8, v);
}

static __device__ __forceinline__ f32x16 mfma32(bf16x8 a, bf16x8 b, f32x16 c){
  return __builtin_amdgcn_mfma_f32_32x32x16_bf16(a, b, c, 0, 0, 0);
}

static __device__ __forceinline__ f32x16 zero16(){
  f32x16 z;
#pragma unroll
  for (int i = 0; i < 16; ++i) z[i] = 0.0f;
  return z;
}

// ---------------- constants ----------------
// B=8 T=2048 E=8 D=128 H=512 ; tokens = 16384
#define WELEM   524288          // E*H*D = E*D*H
#define IMG_EC  49152           // 48 KB per (expert, chunk): wg 16K | wu 16K | wd 16K
// ws layout: [0..15] gamma sums (3 floats used) ; img at +256 (3 MB)

// ---------------- P1: absmean sums ----------------
__global__ void k_gamma(const float* __restrict__ gw, const float* __restrict__ uw,
                        const float* __restrict__ dw, float* __restrict__ sums){
  int t = blockIdx.y;
  const float* w = (t == 0) ? gw : (t == 1 ? uw : dw);
  int base = blockIdx.x * 2048 + threadIdx.x * 8;
  float4 a = *(const float4*)(w + base);
  float4 b = *(const float4*)(w + base + 4);
  float s = fabsf(a.x)+fabsf(a.y)+fabsf(a.z)+fabsf(a.w)
          + fabsf(b.x)+fabsf(b.y)+fabsf(b.z)+fabsf(b.w);
#pragma unroll
  for (int o = 32; o; o >>= 1) s += __shfl_xor(s, o);
  if ((threadIdx.x & 63) == 0) atomicAdd(&sums[t], s);
}

// ---------------- P2: ternary quantize -> fragment-ordered bf16 images ----------------
// gate/up image per (e,c): [ht'(2)][ks(8)][lane(64)][16B]  (B-frag: col h = ht*32+(L&31), k d = ks*16+(L>>5)*8+j)
// down    image per (e,c): [dt(4)][ks'(4)][lane(64)][16B]  (B-frag: col d = dt*32+(L&31), k h = c*64+ks'*16+(L>>5)*8+j)
__global__ void k_quant(const float* __restrict__ gw, const float* __restrict__ uw,
                        const float* __restrict__ dw, const float* __restrict__ sums,
                        unsigned char* __restrict__ img){
  int b  = blockIdx.x;
  int tt = b % 3;
  int c  = (b / 3) & 7;
  int e  = b / 24;
  const float* w = (tt == 0) ? gw : (tt == 1 ? uw : dw);
  float inv = 1.0f / (sums[tt] * (1.0f / 524288.0f) + 1e-8f);
  unsigned char* dst = img + (size_t)(e * 8 + c) * IMG_EC + tt * 16384;
#pragma unroll
  for (int i = 0; i < 4; ++i){
    int grp = threadIdx.x + i * 256;      // 0..1023 (16B groups of 16KB)
    int L = grp & 63, blkid = grp >> 6;
    int srcoff;
    if (tt < 2){
      int ht = blkid >> 3, ks = blkid & 7;
      int h  = c * 64 + ht * 32 + (L & 31);
      int dd = ks * 16 + (L >> 5) * 8;
      srcoff = (e * 512 + h) * 128 + dd;
    } else {
      int dt = blkid >> 2, ksp = blkid & 3;
      int d0 = dt * 32 + (L & 31);
      int h  = c * 64 + ksp * 16 + (L >> 5) * 8;
      srcoff = (e * 128 + d0) * 512 + h;
    }
    float4 f0 = *(const float4*)(w + srcoff);
    float4 f1 = *(const float4*)(w + srcoff + 4);
    float v[8] = {f0.x,f0.y,f0.z,f0.w,f1.x,f1.y,f1.z,f1.w};
    unsigned int o[4];
#pragma unroll
    for (int j = 0; j < 4; ++j){
      float q0 = fminf(1.0f, fmaxf(-1.0f, rintf(v[2*j]   * inv)));
      float q1 = fminf(1.0f, fmaxf(-1.0f, rintf(v[2*j+1] * inv)));
      o[j] = (unsigned int)f2bf(q0) | ((unsigned int)f2bf(q1) << 16);
    }
    *(U4*)(dst + grp * 16) = U4{o[0], o[1], o[2], o[3]};
  }
}

// ---------------- main fused kernel ----------------
// grid (64 token-tiles, 8 experts), 512 threads (8 waves = 4 mw x 2 hw)
// LDS: [0,64K) xt frag image [mt8][ks8][64][16]
//      [64K,96K) WB = wg 16K | wu 16K  (aliased by hidden [mt8][ks'4][64][16] after mm1)
//      [96K,112K) WD = wd 16K
__global__ __launch_bounds__(512) void k_moe(
    const float* __restrict__ x, const float* __restrict__ ew,
    const float* __restrict__ sums, const unsigned char* __restrict__ img,
    float* __restrict__ out){
  extern __shared__ char smem[];
  const int tile = blockIdx.x;
  const int e    = blockIdx.y;
  const int tid  = threadIdx.x;
  const int lane = tid & 63;
  const int wid  = tid >> 6;
  const int mw   = wid >> 1;   // 0..3  (64-token slice)
  const int hw   = wid & 1;    // 0..1  (h-half of chunk / d-half of out)

  const float gg  = sums[0] * (1.0f/524288.0f) + 1e-8f;
  const float gu  = sums[1] * (1.0f/524288.0f) + 1e-8f;
  const float gdn = sums[2] * (1.0f/524288.0f) + 1e-8f;

  // ---- stage x tile: f32 -> bf16 A-fragment image ----
  {
    int s = tid & 15, mh = tid >> 4;        // s: 16B-group within row, mh: row in 32-row block
    int ks = s >> 1, hi = s & 1, L = hi * 32 + mh;
    const float* xb = x + ((size_t)(tile * 256) * 8 + e) * 128;
#pragma unroll
    for (int blk = 0; blk < 8; ++blk){
      const float* src = xb + (size_t)(blk * 32 + mh) * 1024 + s * 8;
      float4 f0 = *(const float4*)src;
      float4 f1 = *(const float4*)(src + 4);
      unsigned int w0 = (unsigned)f2bf(f0.x) | ((unsigned)f2bf(f0.y) << 16);
      unsigned int w1 = (unsigned)f2bf(f0.z) | ((unsigned)f2bf(f0.w) << 16);
      unsigned int w2 = (unsigned)f2bf(f1.x) | ((unsigned)f2bf(f1.y) << 16);
      unsigned int w3 = (unsigned)f2bf(f1.z) | ((unsigned)f2bf(f1.w) << 16);
      *(U4*)(smem + ((size_t)((blk * 8 + ks) * 64 + L) * 16)) = U4{w0, w1, w2, w3};
    }
  }
  __syncthreads();

  f32x16 o00 = zero16(), o01 = zero16(), o10 = zero16(), o11 = zero16();

  char* WB = smem + 65536;
  char* WD = smem + 98304;
  const unsigned char* wsrcbase = img + (size_t)e * 8 * IMG_EC;

  // lane constants for hidden write (C-frag -> A-frag position)
  const int hc   = hw * 32 + (lane & 31);   // h within 64-chunk
  const int ksp  = hc >> 4;
  const int hj2  = (hc & 7) * 2;
  const int lhib = ((hc >> 3) & 1) * 32;
  const int rb   = 4 * (lane >> 5);

  for (int c = 0; c < 8; ++c){
    if (c) __syncthreads();                 // prev mm2 done reading hidden/WD
    // ---- stage weights for this chunk (48 KB, linear copy) ----
    const unsigned char* wsrc = wsrcbase + (size_t)c * IMG_EC;
#pragma unroll
    for (int i = 0; i < 6; ++i){
      int unit = wid * 6 + i;               // 0..47 (1KB units): wg | wu | wd
      U4 v = *(const U4*)(wsrc + unit * 1024 + lane * 16);
      *(U4*)(WB + unit * 1024 + lane * 16) = v;
    }
    __syncthreads();

    // ---- mm1: gate & up, wave tile [64 m x 32 h], K = 128 ----
    f32x16 ag0 = zero16(), ag1 = zero16(), au0 = zero16(), au1 = zero16();
#pragma unroll
    for (int ks = 0; ks < 8; ++ks){
      bf16x8 a0 = ldfrag(smem + (((mw * 2 + 0) * 8 + ks) * 64 + lane) * 16);
      bf16x8 a1 = ldfrag(smem + (((mw * 2 + 1) * 8 + ks) * 64 + lane) * 16);
      bf16x8 bg = ldfrag(WB +          ((hw * 8 + ks) * 64 + lane) * 16);
      bf16x8 bu = ldfrag(WB + 16384 +  ((hw * 8 + ks) * 64 + lane) * 16);
      ag0 = mfma32(a0, bg, ag0);  ag1 = mfma32(a1, bg, ag1);
      au0 = mfma32(a0, bu, au0);  au1 = mfma32(a1, bu, au1);
    }
    __syncthreads();                        // all waves done reading WB

    // ---- hidden = silu(gate*gg) * (up*gu) -> bf16 LDS (A-frag order), aliases WB ----
#pragma unroll
    for (int mt2 = 0; mt2 < 2; ++mt2){
      int mt = mw * 2 + mt2;
      char* hb = WB + ((mt * 4 + ksp) * 64 + lhib) * 16 + hj2;
      f32x16 G = mt2 ? ag1 : ag0;
      f32x16 U = mt2 ? au1 : au0;
#pragma unroll
      for (int r = 0; r < 16; ++r){
        float gv = G[r] * gg;
        float uv = U[r] * gu;
        float hv = (gv / (1.0f + __expf(-gv))) * uv;
        int rm = (r & 3) + 8 * (r >> 2) + rb;
        *(unsigned short*)(hb + rm * 16) = f2bf(hv);
      }
    }
    __syncthreads();                        // hidden visible

    // ---- mm2: out += hidden x down^T, wave tile [64 m x 64 d], K = 64 ----
#pragma unroll
    for (int ks2 = 0; ks2 < 4; ++ks2){
      bf16x8 h0 = ldfrag(WB + (((mw * 2 + 0) * 4 + ks2) * 64 + lane) * 16);
      bf16x8 h1 = ldfrag(WB + (((mw * 2 + 1) * 4 + ks2) * 64 + lane) * 16);
      bf16x8 d0 = ldfrag(WD + (((hw * 2 + 0) * 4 + ks2) * 64 + lane) * 16);
      bf16x8 d1 = ldfrag(WD + (((hw * 2 + 1) * 4 + ks2) * 64 + lane) * 16);
      o00 = mfma32(h0, d0, o00);  o01 = mfma32(h0, d1, o01);
      o10 = mfma32(h1, d0, o10);  o11 = mfma32(h1, d1, o11);
    }
  }

  // ---- epilogue: scale by gamma_down * expert_weight, store f32 ----
#pragma unroll
  for (int mt2 = 0; mt2 < 2; ++mt2){
    int mbase = tile * 256 + mw * 64 + mt2 * 32 + rb;
#pragma unroll
    for (int dt2 = 0; dt2 < 2; ++dt2){
      f32x16 v = mt2 ? (dt2 ? o11 : o10) : (dt2 ? o01 : o00);
      int d = hw * 64 + dt2 * 32 + (lane & 31);
#pragma unroll
      for (int r = 0; r < 16; ++r){
        int token = mbase + (r & 3) + 8 * (r >> 2);
        float scale = gdn * ew[token * 8 + e];
        out[(size_t)(token * 8 + e) * 128 + d] = v[r] * scale;
      }
    }
  }
}

// ---------------- launcher ----------------
extern "C" void kernel_launch(void* const* d_in, const int* in_sizes, int n_in,
                              void* d_out, int out_size, void* d_ws, size_t ws_size,
                              hipStream_t stream){
  const float* x  = (const float*)d_in[0];
  const float* ew = (const float*)d_in[1];
  const float* gw = (const float*)d_in[2];
  const float* uw = (const float*)d_in[3];
  const float* dw = (const float*)d_in[4];
  float* out = (float*)d_out;

  float* sums = (float*)d_ws;
  unsigned char* img = (unsigned char*)d_ws + 256;

  hipMemsetAsync(d_ws, 0, 16, stream);
  k_gamma<<<dim3(256, 3), 256, 0, stream>>>(gw, uw, dw, sums);
  k_quant<<<dim3(192), 256, 0, stream>>>(gw, uw, dw, sums, img);
  k_moe<<<dim3(64, 8), 512, 114688, stream>>>(x, ew, sums, img, out);
}

// Round 2
// 179.794 us; speedup vs baseline: 1.2167x; 1.2167x over previous
//
#include <hip/hip_runtime.h>

// ---------------- types ----------------
typedef __attribute__((ext_vector_type(8)))  __bf16 bf16x8;
typedef __attribute__((ext_vector_type(16))) float  f32x16;

struct U4 { unsigned int x, y, z, w; };

static __device__ __forceinline__ unsigned short f2bf(float f){
  unsigned int u = __builtin_bit_cast(unsigned int, f);
  u += 0x7fffu + ((u >> 16) & 1u);          // round-to-nearest-even
  return (unsigned short)(u >> 16);
}

static __device__ __forceinline__ unsigned pk2(float lo, float hi){
  return (unsigned)f2bf(lo) | ((unsigned)f2bf(hi) << 16);
}

static __device__ __forceinline__ bf16x8 ldfrag(const void* p){
  U4 v = *(const U4*)p;                      // ds_read_b128
  return __builtin_bit_cast(bf16x8, v);
}

static __device__ __forceinline__ f32x16 mfma32(bf16x8 a, bf16x8 b, f32x16 c){
  return __builtin_amdgcn_mfma_f32_32x32x16_bf16(a, b, c, 0, 0, 0);
}

static __device__ __forceinline__ f32x16 zero16(){
  f32x16 z;
#pragma unroll
  for (int i = 0; i < 16; ++i) z[i] = 0.0f;
  return z;
}

// half-wave swap: exchange a's hi-lane values with b's lo-lane values
// (new_a[l>=32] = b[l-32]; new_b[l<32] = a[l+32])
static __device__ __forceinline__ void swap32(unsigned &a, unsigned &b){
  unsigned sa = (unsigned)__shfl_xor((int)a, 32, 64);
  unsigned sb = (unsigned)__shfl_xor((int)b, 32, 64);
  int l = (int)(threadIdx.x & 63);
  unsigned na = (l < 32) ? a : sb;
  unsigned nb = (l < 32) ? sa : b;
  a = na; b = nb;
}

// ---------------- constants ----------------
// B=8 T=2048 E=8 D=128 H=512 ; tokens = 16384
#define IMG_EC  49152           // 48 KB per (expert, chunk): wg 16K | wu 16K | wd 16K
// ws layout: [0..15] gamma sums (3 floats used) ; img at +256 (3 MB)

// ---------------- P1: absmean sums ----------------
__global__ void k_gamma(const float* __restrict__ gw, const float* __restrict__ uw,
                        const float* __restrict__ dw, float* __restrict__ sums){
  int t = blockIdx.y;
  const float* w = (t == 0) ? gw : (t == 1 ? uw : dw);
  int base = blockIdx.x * 2048 + threadIdx.x * 8;
  float4 a = *(const float4*)(w + base);
  float4 b = *(const float4*)(w + base + 4);
  float s = fabsf(a.x)+fabsf(a.y)+fabsf(a.z)+fabsf(a.w)
          + fabsf(b.x)+fabsf(b.y)+fabsf(b.z)+fabsf(b.w);
#pragma unroll
  for (int o = 32; o; o >>= 1) s += __shfl_xor(s, o);
  if ((threadIdx.x & 63) == 0) atomicAdd(&sums[t], s);
}

// ---------------- P2: ternary quantize -> fragment-ordered bf16 images ----------------
// gate/up image per (e,c): [ht(2)][ks(8)][lane(64)][16B]  (frag: h = ht*32+(L&31), k d = ks*16+(L>>5)*8+j)
// down    image per (e,c): [dt(4)][ks'(4)][lane(64)][16B] (frag: d = dt*32+(L&31), k h = c*64+ks'*16+(L>>5)*8+j)
__global__ void k_quant(const float* __restrict__ gw, const float* __restrict__ uw,
                        const float* __restrict__ dw, const float* __restrict__ sums,
                        unsigned char* __restrict__ img){
  int b  = blockIdx.x;
  int tt = b % 3;
  int c  = (b / 3) & 7;
  int e  = b / 24;
  const float* w = (tt == 0) ? gw : (tt == 1 ? uw : dw);
  float inv = 1.0f / (sums[tt] * (1.0f / 524288.0f) + 1e-8f);
  unsigned char* dst = img + (size_t)(e * 8 + c) * IMG_EC + tt * 16384;
#pragma unroll
  for (int i = 0; i < 4; ++i){
    int grp = threadIdx.x + i * 256;      // 0..1023 (16B groups of 16KB)
    int L = grp & 63, blkid = grp >> 6;
    int srcoff;
    if (tt < 2){
      int ht = blkid >> 3, ks = blkid & 7;
      int h  = c * 64 + ht * 32 + (L & 31);
      int dd = ks * 16 + (L >> 5) * 8;
      srcoff = (e * 512 + h) * 128 + dd;
    } else {
      int dt = blkid >> 2, ksp = blkid & 3;
      int d0 = dt * 32 + (L & 31);
      int h  = c * 64 + ksp * 16 + (L >> 5) * 8;
      srcoff = (e * 128 + d0) * 512 + h;
    }
    float4 f0 = *(const float4*)(w + srcoff);
    float4 f1 = *(const float4*)(w + srcoff + 4);
    float v[8] = {f0.x,f0.y,f0.z,f0.w,f1.x,f1.y,f1.z,f1.w};
    unsigned int o[4];
#pragma unroll
    for (int j = 0; j < 4; ++j){
      float q0 = fminf(1.0f, fmaxf(-1.0f, rintf(v[2*j]   * inv)));
      float q1 = fminf(1.0f, fmaxf(-1.0f, rintf(v[2*j+1] * inv)));
      o[j] = (unsigned int)f2bf(q0) | ((unsigned int)f2bf(q1) << 16);
    }
    *(U4*)(dst + grp * 16) = U4{o[0], o[1], o[2], o[3]};
  }
}

// ---------------- main fused kernel ----------------
// grid (64 token-tiles, 8 experts), 512 threads (8 waves), wave owns 32 tokens.
// Swapped mm1: C1 = mfma(W_gate/up, x^T)  -> C col = token (lane&31), row = h.
// Hidden converted in-register (pack + half-wave swap) into mm2's B-frags.
// mm2: out^T = mfma(W_down, hidden^T)     -> C col = token, row = d.
// LDS: single 48KB weight buffer per chunk; staging is async-split (T14).
__global__ __launch_bounds__(512, 2) void k_moe(
    const float* __restrict__ x, const float* __restrict__ ew,
    const float* __restrict__ sums, const unsigned char* __restrict__ img,
    float* __restrict__ out){
  __shared__ char WB[49152];
  const int tile = blockIdx.x;
  const int e    = blockIdx.y;
  const int tid  = threadIdx.x;
  const int lane = tid & 63;
  const int wid  = tid >> 6;
  const int col  = lane & 31;
  const int hi   = lane >> 5;
  const int token = tile * 256 + wid * 32 + col;

  const float gg  = sums[0] * (1.0f/524288.0f) + 1e-8f;
  const float gu  = sums[1] * (1.0f/524288.0f) + 1e-8f;
  const float gdn = sums[2] * (1.0f/524288.0f) + 1e-8f;
  const float osc = gdn * ew[token * 8 + e];

  // ---- x fragments in registers: lane holds x[token][ks*16 + hi*8 .. +8) ----
  const float* xrow = x + ((size_t)token * 8 + e) * 128 + hi * 8;
  bf16x8 xf[8];
#pragma unroll
  for (int ks = 0; ks < 8; ++ks){
    float4 f0 = *(const float4*)(xrow + ks * 16);
    float4 f1 = *(const float4*)(xrow + ks * 16 + 4);
    U4 u{pk2(f0.x,f0.y), pk2(f0.z,f0.w), pk2(f1.x,f1.y), pk2(f1.z,f1.w)};
    xf[ks] = __builtin_bit_cast(bf16x8, u);
  }

  f32x16 O0 = zero16(), O1 = zero16(), O2 = zero16(), O3 = zero16();

  const unsigned char* wsrc0 = img + (size_t)e * 8 * IMG_EC;

  // preload chunk 0 weights into registers
  U4 stg[6];
#pragma unroll
  for (int i = 0; i < 6; ++i)
    stg[i] = *(const U4*)(wsrc0 + (size_t)(tid + i * 512) * 16);

  for (int c = 0; c < 8; ++c){
    if (c) __syncthreads();                 // prev chunk's compute done reading WB
#pragma unroll
    for (int i = 0; i < 6; ++i)
      *(U4*)(WB + (tid + i * 512) * 16) = stg[i];
    __syncthreads();                        // WB ready

    if (c < 7){                             // issue next chunk's loads under compute
      const unsigned char* wsrc = wsrc0 + (size_t)(c + 1) * IMG_EC;
#pragma unroll
      for (int i = 0; i < 6; ++i)
        stg[i] = *(const U4*)(wsrc + (size_t)(tid + i * 512) * 16);
    }

    // ---- mm1: C = W(h64 x d128) * x^T(d128 x t32), 32 mfma, 4 chains ----
    f32x16 Cg0 = zero16(), Cg1 = zero16(), Cu0 = zero16(), Cu1 = zero16();
#pragma unroll
    for (int ks = 0; ks < 8; ++ks){
      bf16x8 ag0 = ldfrag(WB +         ((0 * 8 + ks) * 64 + lane) * 16);
      bf16x8 ag1 = ldfrag(WB +         ((1 * 8 + ks) * 64 + lane) * 16);
      bf16x8 au0 = ldfrag(WB + 16384 + ((0 * 8 + ks) * 64 + lane) * 16);
      bf16x8 au1 = ldfrag(WB + 16384 + ((1 * 8 + ks) * 64 + lane) * 16);
      Cg0 = mfma32(ag0, xf[ks], Cg0);
      Cg1 = mfma32(ag1, xf[ks], Cg1);
      Cu0 = mfma32(au0, xf[ks], Cu0);
      Cu1 = mfma32(au1, xf[ks], Cu1);
    }

    // ---- hidden = silu(g*gg)*(u*gu), in-register -> 4 B-frags (K16 steps) ----
    bf16x8 hf[4];
#pragma unroll
    for (int ht = 0; ht < 2; ++ht){
      const f32x16& G = ht ? Cg1 : Cg0;
      const f32x16& U = ht ? Cu1 : Cu0;
#pragma unroll
      for (int s = 0; s < 2; ++s){
        float h[8];
#pragma unroll
        for (int j = 0; j < 8; ++j){
          float gv = G[s * 8 + j] * gg;
          float uv = U[s * 8 + j] * gu;
          h[j] = (gv / (1.0f + __expf(-gv))) * uv;
        }
        unsigned w0 = pk2(h[0], h[1]);      // rows +0,+1 (lo) / +4,+5 (hi)
        unsigned w1 = pk2(h[2], h[3]);
        unsigned w2 = pk2(h[4], h[5]);      // rows +8,+9 (lo) / +12,+13 (hi)
        unsigned w3 = pk2(h[6], h[7]);
        swap32(w0, w2);                     // -> lo:(0,1)(4,5) hi:(8,9)(12,13)
        swap32(w1, w3);
        U4 u{w0, w1, w2, w3};
        hf[ht * 2 + s] = __builtin_bit_cast(bf16x8, u);
      }
    }

    // ---- mm2: O^T += W_down(d128 x h64) * hidden^T(h64 x t32), 16 mfma ----
#pragma unroll
    for (int ks2 = 0; ks2 < 4; ++ks2){
      bf16x8 d0 = ldfrag(WB + 32768 + ((0 * 4 + ks2) * 64 + lane) * 16);
      bf16x8 d1 = ldfrag(WB + 32768 + ((1 * 4 + ks2) * 64 + lane) * 16);
      bf16x8 d2 = ldfrag(WB + 32768 + ((2 * 4 + ks2) * 64 + lane) * 16);
      bf16x8 d3 = ldfrag(WB + 32768 + ((3 * 4 + ks2) * 64 + lane) * 16);
      O0 = mfma32(d0, hf[ks2], O0);
      O1 = mfma32(d1, hf[ks2], O1);
      O2 = mfma32(d2, hf[ks2], O2);
      O3 = mfma32(d3, hf[ks2], O3);
    }
  }

  // ---- epilogue: lane holds one token, 64 d-values; float4 stores ----
  float* orow = out + ((size_t)token * 8 + e) * 128 + hi * 4;
#pragma unroll
  for (int dt = 0; dt < 4; ++dt){
    const f32x16& O = dt == 0 ? O0 : dt == 1 ? O1 : dt == 2 ? O2 : O3;
#pragma unroll
    for (int q = 0; q < 4; ++q){
      float4 v{O[q*4+0]*osc, O[q*4+1]*osc, O[q*4+2]*osc, O[q*4+3]*osc};
      *(float4*)(orow + dt * 32 + q * 8) = v;   // d = dt*32 + q*8 + hi*4 + j
    }
  }
}

// ---------------- launcher ----------------
extern "C" void kernel_launch(void* const* d_in, const int* in_sizes, int n_in,
                              void* d_out, int out_size, void* d_ws, size_t ws_size,
                              hipStream_t stream){
  const float* x  = (const float*)d_in[0];
  const float* ew = (const float*)d_in[1];
  const float* gw = (const float*)d_in[2];
  const float* uw = (const float*)d_in[3];
  const float* dw = (const float*)d_in[4];
  float* out = (float*)d_out;

  float* sums = (float*)d_ws;
  unsigned char* img = (unsigned char*)d_ws + 256;

  hipMemsetAsync(d_ws, 0, 16, stream);
  k_gamma<<<dim3(256, 3), 256, 0, stream>>>(gw, uw, dw, sums);
  k_quant<<<dim3(192), 256, 0, stream>>>(gw, uw, dw, sums, img);
  k_moe<<<dim3(64, 8), 512, 0, stream>>>(x, ew, sums, img, out);
}

// Round 3
// 177.125 us; speedup vs baseline: 1.2351x; 1.0151x over previous
//
#include <hip/hip_runtime.h>

// ---------------- types ----------------
typedef __attribute__((ext_vector_type(8)))  __bf16 bf16x8;
typedef __attribute__((ext_vector_type(16))) float  f32x16;

struct U4 { unsigned int x, y, z, w; };

static __device__ __forceinline__ unsigned short f2bf(float f){
  unsigned int u = __builtin_bit_cast(unsigned int, f);
  u += 0x7fffu + ((u >> 16) & 1u);          // round-to-nearest-even
  return (unsigned short)(u >> 16);
}

static __device__ __forceinline__ unsigned pk2(float lo, float hi){
  return (unsigned)f2bf(lo) | ((unsigned)f2bf(hi) << 16);
}

static __device__ __forceinline__ bf16x8 ldfrag(const void* p){
  U4 v = *(const U4*)p;                      // ds_read_b128
  return __builtin_bit_cast(bf16x8, v);
}

static __device__ __forceinline__ f32x16 mfma32(bf16x8 a, bf16x8 b, f32x16 c){
  return __builtin_amdgcn_mfma_f32_32x32x16_bf16(a, b, c, 0, 0, 0);
}

static __device__ __forceinline__ f32x16 zero16(){
  f32x16 z;
#pragma unroll
  for (int i = 0; i < 16; ++i) z[i] = 0.0f;
  return z;
}

// async 16B global -> LDS (linear: wave-uniform base + lane*16)
static __device__ __forceinline__ void gload16(const void* g, void* l){
  __builtin_amdgcn_global_load_lds(
      (const __attribute__((address_space(1))) unsigned int*)g,
      (__attribute__((address_space(3))) unsigned int*)l, 16, 0, 0);
}

// half-wave swap: new_a[l>=32] = b[l-32]; new_b[l<32] = a[l+32]
static __device__ __forceinline__ void swap32(unsigned &a, unsigned &b){
  unsigned sa = (unsigned)__shfl_xor((int)a, 32, 64);
  unsigned sb = (unsigned)__shfl_xor((int)b, 32, 64);
  int l = (int)(threadIdx.x & 63);
  unsigned na = (l < 32) ? a : sb;
  unsigned nb = (l < 32) ? sa : b;
  a = na; b = nb;
}

// ---------------- constants ----------------
// B=8 T=2048 E=8 D=128 H=512 ; tokens = 16384
#define IMG_EC  49152           // 48 KB per (expert, chunk): wg 16K | wu 16K | wd 16K

// ---------------- P1: absmean sums ----------------
__global__ void k_gamma(const float* __restrict__ gw, const float* __restrict__ uw,
                        const float* __restrict__ dw, float* __restrict__ sums){
  int t = blockIdx.y;
  const float* w = (t == 0) ? gw : (t == 1 ? uw : dw);
  int base = blockIdx.x * 2048 + threadIdx.x * 8;
  float4 a = *(const float4*)(w + base);
  float4 b = *(const float4*)(w + base + 4);
  float s = fabsf(a.x)+fabsf(a.y)+fabsf(a.z)+fabsf(a.w)
          + fabsf(b.x)+fabsf(b.y)+fabsf(b.z)+fabsf(b.w);
#pragma unroll
  for (int o = 32; o; o >>= 1) s += __shfl_xor(s, o);
  if ((threadIdx.x & 63) == 0) atomicAdd(&sums[t], s);
}

// ---------------- P2: ternary quantize -> fragment-ordered bf16 images ----------------
__global__ void k_quant(const float* __restrict__ gw, const float* __restrict__ uw,
                        const float* __restrict__ dw, const float* __restrict__ sums,
                        unsigned char* __restrict__ img){
  int b  = blockIdx.x;
  int tt = b % 3;
  int c  = (b / 3) & 7;
  int e  = b / 24;
  const float* w = (tt == 0) ? gw : (tt == 1 ? uw : dw);
  float inv = 1.0f / (sums[tt] * (1.0f / 524288.0f) + 1e-8f);
  unsigned char* dst = img + (size_t)(e * 8 + c) * IMG_EC + tt * 16384;
#pragma unroll
  for (int i = 0; i < 4; ++i){
    int grp = threadIdx.x + i * 256;      // 0..1023 (16B groups of 16KB)
    int L = grp & 63, blkid = grp >> 6;
    int srcoff;
    if (tt < 2){
      int ht = blkid >> 3, ks = blkid & 7;
      int h  = c * 64 + ht * 32 + (L & 31);
      int dd = ks * 16 + (L >> 5) * 8;
      srcoff = (e * 512 + h) * 128 + dd;
    } else {
      int dt = blkid >> 2, ksp = blkid & 3;
      int d0 = dt * 32 + (L & 31);
      int h  = c * 64 + ksp * 16 + (L >> 5) * 8;
      srcoff = (e * 128 + d0) * 512 + h;
    }
    float4 f0 = *(const float4*)(w + srcoff);
    float4 f1 = *(const float4*)(w + srcoff + 4);
    float v[8] = {f0.x,f0.y,f0.z,f0.w,f1.x,f1.y,f1.z,f1.w};
    unsigned int o[4];
#pragma unroll
    for (int j = 0; j < 4; ++j){
      float q0 = fminf(1.0f, fmaxf(-1.0f, rintf(v[2*j]   * inv)));
      float q1 = fminf(1.0f, fmaxf(-1.0f, rintf(v[2*j+1] * inv)));
      o[j] = (unsigned int)f2bf(q0) | ((unsigned int)f2bf(q1) << 16);
    }
    *(U4*)(dst + grp * 16) = U4{o[0], o[1], o[2], o[3]};
  }
}

// ---------------- main fused kernel ----------------
// grid (64, 8), 512 threads (8 waves), wave owns 32 tokens.
// Swapped mm1: C = mfma(W, x^T) -> col = token; hidden stays in registers
// (pack + half-wave swap) and feeds mm2 B-frags. Weights double-buffered in
// LDS via global_load_lds (T3 2-phase). 1 block/CU pinned -> 256-reg budget.
__global__ __attribute__((amdgpu_waves_per_eu(2, 2))) __launch_bounds__(512)
void k_moe(const float* __restrict__ x, const float* __restrict__ ew,
           const float* __restrict__ sums, const unsigned char* __restrict__ img,
           float* __restrict__ out){
  extern __shared__ char smem[];            // 2 x 48 KB
  const int tile = blockIdx.x;
  const int e    = blockIdx.y;
  const int tid  = threadIdx.x;
  const int lane = tid & 63;
  const int wid  = tid >> 6;
  const int col  = lane & 31;
  const int hi   = lane >> 5;
  const int token = tile * 256 + wid * 32 + col;

  const float gg  = sums[0] * (1.0f/524288.0f) + 1e-8f;
  const float gu  = sums[1] * (1.0f/524288.0f) + 1e-8f;
  const float gdn = sums[2] * (1.0f/524288.0f) + 1e-8f;

  const unsigned char* wsrc0 = img + (size_t)e * 8 * IMG_EC;

  // ---- stage chunk 0 into buf 0 (async, direct to LDS) ----
#pragma unroll
  for (int i = 0; i < 6; ++i)
    gload16(wsrc0 + (size_t)(tid + i * 512) * 16, smem + (tid + i * 512) * 16);

  // ---- x fragments in registers: lane holds x[token][ks*16 + hi*8 .. +8) ----
  const float* xrow = x + ((size_t)token * 8 + e) * 128 + hi * 8;
  bf16x8 xf[8];
#pragma unroll
  for (int ks = 0; ks < 8; ++ks){
    float4 f0 = *(const float4*)(xrow + ks * 16);
    float4 f1 = *(const float4*)(xrow + ks * 16 + 4);
    U4 u{pk2(f0.x,f0.y), pk2(f0.z,f0.w), pk2(f1.x,f1.y), pk2(f1.z,f1.w)};
    xf[ks] = __builtin_bit_cast(bf16x8, u);
  }

  f32x16 O0 = zero16(), O1 = zero16(), O2 = zero16(), O3 = zero16();

  __syncthreads();                          // drains vmcnt: buf0 ready

#pragma unroll 2
  for (int c = 0; c < 8; ++c){
    const char* cur = smem + (c & 1) * 49152;
    // ---- issue next chunk's staging first (stays in flight under compute) ----
    if (c < 7){
      const unsigned char* wsrc = wsrc0 + (size_t)(c + 1) * IMG_EC;
      char* nxt = smem + ((c + 1) & 1) * 49152;
#pragma unroll
      for (int i = 0; i < 6; ++i)
        gload16(wsrc + (size_t)(tid + i * 512) * 16, nxt + (tid + i * 512) * 16);
    }

    // ---- mm1 + silu per 32-h half (keeps C-liveness at 32 regs) ----
    bf16x8 hf[4];
#pragma unroll
    for (int ht = 0; ht < 2; ++ht){
      f32x16 Cg = zero16(), Cu = zero16();
#pragma unroll
      for (int ks = 0; ks < 8; ++ks){
        bf16x8 ag = ldfrag(cur +         ((ht * 8 + ks) * 64 + lane) * 16);
        bf16x8 au = ldfrag(cur + 16384 + ((ht * 8 + ks) * 64 + lane) * 16);
        Cg = mfma32(ag, xf[ks], Cg);
        Cu = mfma32(au, xf[ks], Cu);
      }
#pragma unroll
      for (int s = 0; s < 2; ++s){
        float h[8];
#pragma unroll
        for (int j = 0; j < 8; ++j){
          float gv = Cg[s * 8 + j] * gg;
          float uv = Cu[s * 8 + j] * gu;
          // silu(gv)*uv with fast rcp (error << bf16 rounding)
          h[j] = gv * __builtin_amdgcn_rcpf(1.0f + __expf(-gv)) * uv;
        }
        unsigned w0 = pk2(h[0], h[1]);
        unsigned w1 = pk2(h[2], h[3]);
        unsigned w2 = pk2(h[4], h[5]);
        unsigned w3 = pk2(h[6], h[7]);
        swap32(w0, w2);
        swap32(w1, w3);
        U4 u{w0, w1, w2, w3};
        hf[ht * 2 + s] = __builtin_bit_cast(bf16x8, u);
      }
    }

    // ---- mm2: O^T += W_down(d128 x h64) * hidden^T(h64 x t32) ----
#pragma unroll
    for (int ks2 = 0; ks2 < 4; ++ks2){
      bf16x8 d0 = ldfrag(cur + 32768 + ((0 * 4 + ks2) * 64 + lane) * 16);
      bf16x8 d1 = ldfrag(cur + 32768 + ((1 * 4 + ks2) * 64 + lane) * 16);
      bf16x8 d2 = ldfrag(cur + 32768 + ((2 * 4 + ks2) * 64 + lane) * 16);
      bf16x8 d3 = ldfrag(cur + 32768 + ((3 * 4 + ks2) * 64 + lane) * 16);
      O0 = mfma32(d0, hf[ks2], O0);
      O1 = mfma32(d1, hf[ks2], O1);
      O2 = mfma32(d2, hf[ks2], O2);
      O3 = mfma32(d3, hf[ks2], O3);
    }

    if (c < 7) __syncthreads();             // drains vmcnt+lgkm: nxt ready, cur reusable
  }

  // ---- epilogue: lane holds one token, 64 d-values; float4 stores ----
  const float osc = gdn * ew[token * 8 + e];
  float* orow = out + ((size_t)token * 8 + e) * 128 + hi * 4;
#pragma unroll
  for (int dt = 0; dt < 4; ++dt){
    const f32x16& O = dt == 0 ? O0 : dt == 1 ? O1 : dt == 2 ? O2 : O3;
#pragma unroll
    for (int q = 0; q < 4; ++q){
      float4 v{O[q*4+0]*osc, O[q*4+1]*osc, O[q*4+2]*osc, O[q*4+3]*osc};
      *(float4*)(orow + dt * 32 + q * 8) = v;   // d = dt*32 + q*8 + hi*4 + j
    }
  }
}

// ---------------- launcher ----------------
extern "C" void kernel_launch(void* const* d_in, const int* in_sizes, int n_in,
                              void* d_out, int out_size, void* d_ws, size_t ws_size,
                              hipStream_t stream){
  const float* x  = (const float*)d_in[0];
  const float* ew = (const float*)d_in[1];
  const float* gw = (const float*)d_in[2];
  const float* uw = (const float*)d_in[3];
  const float* dw = (const float*)d_in[4];
  float* out = (float*)d_out;

  float* sums = (float*)d_ws;
  unsigned char* img = (unsigned char*)d_ws + 256;

  hipMemsetAsync(d_ws, 0, 16, stream);
  k_gamma<<<dim3(256, 3), 256, 0, stream>>>(gw, uw, dw, sums);
  k_quant<<<dim3(192), 256, 0, stream>>>(gw, uw, dw, sums, img);
  k_moe<<<dim3(64, 8), 512, 98304, stream>>>(x, ew, sums, img, out);
}